// Round 5
// baseline (217.517 us; speedup 1.0000x reference)
//
#include <hip/hip_runtime.h>
#include <hip/hip_bf16.h>

// Problem constants
#define BB 16
#define CC 64
#define HH 64
#define WW 64
#define QQ 8192
#define HID 256
#define KK 576            // C*9
#define HT 66             // H + 2 halo
#define FROW 264          // 257 channels padded to 264 (16B-aligned rows)

typedef short short8 __attribute__((ext_vector_type(8)));
typedef short sv4    __attribute__((ext_vector_type(4)));
typedef float f32x4  __attribute__((ext_vector_type(4)));

__device__ __forceinline__ short f2bf(float f) {
    union { float f; unsigned u; } v; v.f = f;
    unsigned r = v.u + 0x7fffu + ((v.u >> 16) & 1u);
    return (short)(r >> 16);
}
__device__ __forceinline__ float bf2f(short s) {
    union { unsigned u; float f; } v; v.u = ((unsigned)(unsigned short)s) << 16;
    return v.f;
}
// Barrier that only drains LDS (lgkmcnt) — does NOT force vmcnt(0), so global
// prefetches issued before it stay in flight.
__device__ __forceinline__ void barrier_lds() {
    asm volatile("s_waitcnt lgkmcnt(0)" ::: "memory");
    __builtin_amdgcn_s_barrier();
    asm volatile("" ::: "memory");
}

// ---------------------------------------------------------------------------
// Kernel T+P fused: weight repack (grid-stride over first pass) + feat
// transpose to channel-last bf16 with zero halo.
// ---------------------------------------------------------------------------
__global__ __launch_bounds__(256) void prep_transpose_k(const float* __restrict__ feat,
                                                        const float* __restrict__ w2,
                                                        const float* __restrict__ w3,
                                                        const float* __restrict__ b3,
                                                        short* __restrict__ featT,
                                                        short* __restrict__ w3cT,
                                                        short* __restrict__ w2bT) {
    __shared__ float ftile[64][65];
    const int t = threadIdx.x;
    const int gidx = blockIdx.x * 256 + t;   // grid = 1056 wgs -> 270336 threads

    // --- weight prep (single pass, guarded) ---
    if (gidx < 272 * KK) {
        int n = gidx / KK, kk = gidx - n * KK;
        int pos = kk >> 6, c = kk & 63;
        float v = 0.f;
        if (n < 256)      v = w3[n * KK + c * 9 + pos];
        else if (n == 256) v = b3[c * 9 + pos];
        w3cT[gidx] = f2bf(v);
    }
    if (gidx < 256 * 256) {
        int n = gidx >> 8, k = gidx & 255;
        w2bT[gidx] = f2bf(w2[k * 256 + n]);
    }

    // --- transpose ---
    const int b = blockIdx.x / HT;
    const int yy = blockIdx.x - b * HT;
    short* out_row = featT + ((b * HT + yy) * HT) * 64;   // plane of HT*64 shorts

    if (yy == 0 || yy == HT - 1) {
        for (int idx = t; idx < HT * 64; idx += 256) out_row[idx] = 0;
        return;
    }
    const int y = yy - 1;
    const float* src = feat + ((b * CC) * HH + y) * WW;   // + c*HH*WW + x
#pragma unroll
    for (int i = 0; i < 16; ++i) {
        int idx = i * 256 + t;
        int c = idx >> 6, x = idx & 63;
        ftile[c][x] = src[c * (HH * WW) + x];
    }
    // halo columns (xx=0 and xx=65)
    if (t < 64) out_row[t] = 0;
    else if (t < 128) out_row[(HT - 1) * 64 + (t - 64)] = 0;
    __syncthreads();
#pragma unroll
    for (int i = 0; i < 16; ++i) {
        int idx = i * 256 + t;
        int x = idx >> 6, c = idx & 63;
        out_row[(x + 1) * 64 + c] = f2bf(ftile[c][x]);
    }
}

// ---------------------------------------------------------------------------
// Kernel C v3: conv as implicit GEMM with explicit depth-1 software pipeline.
//   wg = (b,y): M=64 pixels, N=272, K=576 (18 k-steps of 32).
//   bfr (global) and af (LDS) for step s+1 are loaded into double-buffered
//   registers before step s's MFMAs -> loads overlap MFMA issue instead of
//   each being a serial full-latency wait (R4: VGPR=80, MfmaUtil 14%, all
//   pipes <15% busy -> zero MLP was the bottleneck).
//   LDS = slab only (26.9 KB); epilogue reuses it in two 32-row halves.
// ---------------------------------------------------------------------------
#define SLAB_STRIDE 68   // 64 ch + 4 pad; 136 B rows (8B-aligned -> ds b64)
__global__ __launch_bounds__(256, 3) void conv_k(const short* __restrict__ featT,
                                                 const short* __restrict__ w3cT,
                                                 short* __restrict__ F) {
    __shared__ short lds[3 * HT * SLAB_STRIDE];   // 13464 shorts = 26,928 B
    const int t = threadIdx.x;
    const int wave = t >> 6, lane = t & 63, quad = lane >> 4, ln16 = lane & 15;
    const int b = blockIdx.x >> 6, y = blockIdx.x & 63;

    f32x4 acc[4][5];
#pragma unroll
    for (int a = 0; a < 4; ++a)
#pragma unroll
        for (int i = 0; i < 5; ++i) acc[a][i] = (f32x4){0.f, 0.f, 0.f, 0.f};

    short8 bfrB[2][5];
    short8 afB[2][4];

    auto load_bfr = [&](int buf, int st) {
        const int pos = st >> 1, ks = st & 1;
#pragma unroll
        for (int i = 0; i < 5; ++i) {
            int sub = (i < 4) ? (wave + 4 * i) : 16;
            int n = sub * 16 + ln16;
            bfrB[buf][i] = *(const short8*)(w3cT + n * KK + pos * 64 + ks * 32 + quad * 8);
        }
    };
    auto load_af = [&](int buf, int st) {
        const int pos = st >> 1, ks = st & 1;
        const int di = pos / 3, dj = pos - di * 3;
#pragma unroll
        for (int ms = 0; ms < 4; ++ms) {
            const short* ap = &lds[(di * HT + ms * 16 + ln16 + dj) * SLAB_STRIDE + ks * 32 + quad * 8];
            sv4 a0 = *(const sv4*)ap;
            sv4 a1 = *(const sv4*)(ap + 4);
            afB[buf][ms] = __builtin_shufflevector(a0, a1, 0, 1, 2, 3, 4, 5, 6, 7);
        }
    };

    // Stage slab: featT rows y..y+2 are contiguous (3*66*64 = 12672 shorts)
    const short* slabsrc = featT + b * (HT * HT * 64) + y * (HT * 64);
#pragma unroll
    for (int it = 0; it < 7; ++it) {
        int i = it * 256 + t;             // chunk of 8 shorts; never straddles a row
        if (i < 1584) {
            short8 v = *(const short8*)(slabsrc + i * 8);
            int row = i >> 3, cs = (i & 7) * 8;
            short* d = &lds[row * SLAB_STRIDE + cs];
            *(sv4*)d       = __builtin_shufflevector(v, v, 0, 1, 2, 3);
            *(sv4*)(d + 4) = __builtin_shufflevector(v, v, 4, 5, 6, 7);
        }
    }
    load_bfr(0, 0);        // global prefetch overlaps the barrier drain
    __syncthreads();
    load_af(0, 0);

#pragma unroll
    for (int st = 0; st < 18; ++st) {
        const int cur = st & 1, nxt = cur ^ 1;
        if (st < 17) {
            load_bfr(nxt, st + 1);
            load_af(nxt, st + 1);
        }
#pragma unroll
        for (int i = 0; i < 5; ++i)
#pragma unroll
            for (int ms = 0; ms < 4; ++ms)
                acc[ms][i] = __builtin_amdgcn_mfma_f32_16x16x32_bf16(afB[cur][ms], bfrB[cur][i], acc[ms][i], 0, 0, 0);
    }

    // Epilogue: two 32-row halves through the slab LDS, full-line stores.
#pragma unroll
    for (int h = 0; h < 2; ++h) {
        __syncthreads();
#pragma unroll
        for (int i = 0; i < 5; ++i) {
            int sub = (i < 4) ? (wave + 4 * i) : 16;
            int n = sub * 16 + ln16;
            bool store = (i < 4) || (wave == 0 && n < FROW);
            if (store) {
#pragma unroll
                for (int ms2 = 0; ms2 < 2; ++ms2) {
                    int ms = h * 2 + ms2;
#pragma unroll
                    for (int r = 0; r < 4; ++r) {
                        int xl = ms2 * 16 + quad * 4 + r;      // local row 0..31
                        lds[xl * FROW + n] = f2bf(acc[ms][i][r]);
                    }
                }
            }
        }
        __syncthreads();
        short8* dst = (short8*)(F + ((long)(b * 64 + y) * 64 + h * 32) * FROW);
        const short8* src8 = (const short8*)lds;
        for (int idx = t; idx < (32 * FROW) / 8; idx += 256)
            dst[idx] = src8[idx];
    }
}

// ---------------------------------------------------------------------------
// Kernel M v3: transposed-H2, register combine, vmem-transparent barriers,
// plus explicit prefetch: w1/b1/b2/F/w2bT(s=0) issued before the first
// barrier; w2bT pipelined one s-step ahead through the MFMA loop.
// ---------------------------------------------------------------------------
#define HSTRIDE 264
__global__ __launch_bounds__(256, 3) void mlp_k(const float* __restrict__ coord,
                                                const float* __restrict__ cell,
                                                const float* __restrict__ w1,
                                                const float* __restrict__ b1,
                                                const float* __restrict__ b2v,
                                                const short* __restrict__ w2bT,
                                                const short* __restrict__ F,
                                                float* __restrict__ out) {
    __shared__ float inp_s[64][3];
    __shared__ short H_lds[64 * HSTRIDE];
    __shared__ float red_s[64][4];

    const int t = threadIdx.x;
    const int wave = t >> 6, lane = t & 63, quad = lane >> 4, ln16 = lane & 15;
    const int qbase = blockIdx.x * 64;
    const int b = qbase >> 13;            // Q = 8192

    // --- coords: every wave computes all 64 queries (lane = query) ---
    const int g = qbase + lane;
    const float2 cc = *(const float2*)(coord + g * 2);
    const float2 ce = *(const float2*)(cell + g * 2);
    const float coy = cc.x - ce.x * 0.5f, cox = cc.y - ce.y * 0.5f;
    const float cqy = fminf(fmaxf(coy + 1e-6f, -0.999999f), 0.999999f);
    const float cqx = fminf(fmaxf(cox + 1e-6f, -0.999999f), 0.999999f);
    int iy = (int)rintf(((cqy + 1.0f) * 64.0f - 1.0f) * 0.5f); iy = min(max(iy, 0), 63);
    int ix = (int)rintf(((cqx + 1.0f) * 64.0f - 1.0f) * 0.5f); ix = min(max(ix, 0), 63);
    const int lin = iy * 64 + ix;
    const float in0 = (coy - ((float)iy * (1.0f / 32.0f) - 1.0f)) * 32.0f;
    const float in1 = (cox - ((float)ix * (1.0f / 32.0f) - 1.0f)) * 32.0f;
    const float in2 = ce.x * 32.0f;

    // --- F prefetch: fv[ms][i] = F[lin[ms*16+ln16]][wave*64 + i*16 + quad*4 .. +3]
    const short* Fb = F + (long)b * 4096 * FROW;
    sv4 fv[4][4];
#pragma unroll
    for (int ms = 0; ms < 4; ++ms) {
        int linm = __shfl(lin, ms * 16 + ln16, 64);
        const short* Fr = Fb + (long)linm * FROW + wave * 64 + quad * 4;
#pragma unroll
        for (int i = 0; i < 4; ++i) fv[ms][i] = *(const sv4*)(Fr + i * 16);
    }
    const short fb = Fb[(long)lin * FROW + 256];   // b3 column

    // --- prefetch H1 weights, b2 quad, and w2bT fragments for s=0 ---
    const float w10 = w1[t], w11 = w1[256 + t], w12 = w1[512 + t], b1t = b1[t];
    f32x4 b2q[4];
#pragma unroll
    for (int i = 0; i < 4; ++i)
        b2q[i] = *(const f32x4*)(b2v + wave * 64 + i * 16 + quad * 4);
    short8 wfB[2][4];
#pragma unroll
    for (int i = 0; i < 4; ++i)
        wfB[0][i] = *(const short8*)(w2bT + (wave * 64 + i * 16 + ln16) * 256 + quad * 8);

    if (t < 64) { inp_s[t][0] = in0; inp_s[t][1] = in1; inp_s[t][2] = in2; }
    barrier_lds();

    // --- H1: thread t computes hidden column t for all 64 queries ---
#pragma unroll 8
    for (int m = 0; m < 64; ++m) {
        float v = fmaf(inp_s[m][0], w10, fmaf(inp_s[m][1], w11, fmaf(inp_s[m][2], w12, b1t)));
        H_lds[m * HSTRIDE + t] = f2bf(fmaxf(v, 0.f));
    }
    barrier_lds();

    // --- H2^T: acc2[i][ms] = D[row = n-subtile i][col = m-subtile ms] ---
    f32x4 acc2[4][4];
#pragma unroll
    for (int i = 0; i < 4; ++i)
#pragma unroll
        for (int ms = 0; ms < 4; ++ms) acc2[i][ms] = (f32x4){0.f, 0.f, 0.f, 0.f};
#pragma unroll
    for (int s = 0; s < 8; ++s) {
        const int cur = s & 1, nxt = cur ^ 1;
        if (s < 7) {
#pragma unroll
            for (int i = 0; i < 4; ++i)
                wfB[nxt][i] = *(const short8*)(w2bT + (wave * 64 + i * 16 + ln16) * 256 + (s + 1) * 32 + quad * 8);
        }
        short8 hf[4];
#pragma unroll
        for (int ms = 0; ms < 4; ++ms)
            hf[ms] = *(const short8*)(&H_lds[(ms * 16 + ln16) * HSTRIDE + s * 32 + quad * 8]);
#pragma unroll
        for (int i = 0; i < 4; ++i)
#pragma unroll
            for (int ms = 0; ms < 4; ++ms)
                acc2[i][ms] = __builtin_amdgcn_mfma_f32_16x16x32_bf16(wfB[cur][i], hf[ms], acc2[i][ms], 0, 0, 0);
    }

    // --- combine in registers: pred[m] += relu(H2+b2)[n] * F[lin[m]][n] ---
    float part[4] = {0.f, 0.f, 0.f, 0.f};
#pragma unroll
    for (int i = 0; i < 4; ++i) {
#pragma unroll
        for (int ms = 0; ms < 4; ++ms)
#pragma unroll
            for (int r = 0; r < 4; ++r)
                part[ms] = fmaf(fmaxf(acc2[i][ms][r] + b2q[i][r], 0.f), bf2f(fv[ms][i][r]), part[ms]);
    }
#pragma unroll
    for (int ms = 0; ms < 4; ++ms) {
        part[ms] += __shfl_xor(part[ms], 16, 64);
        part[ms] += __shfl_xor(part[ms], 32, 64);
    }
    if (quad == 0) {
#pragma unroll
        for (int ms = 0; ms < 4; ++ms) red_s[ms * 16 + ln16][wave] = part[ms];
    }
    barrier_lds();
    if (t < 64)
        out[qbase + t] = red_s[t][0] + red_s[t][1] + red_s[t][2] + red_s[t][3] + bf2f(fb);
}

// ---------------------------------------------------------------------------
extern "C" void kernel_launch(void* const* d_in, const int* in_sizes, int n_in,
                              void* d_out, int out_size, void* d_ws, size_t ws_size,
                              hipStream_t stream) {
    const float* feat  = (const float*)d_in[0];
    const float* coord = (const float*)d_in[1];
    const float* cell  = (const float*)d_in[2];
    const float* w1    = (const float*)d_in[3];
    const float* b1    = (const float*)d_in[4];
    const float* w2    = (const float*)d_in[5];
    const float* b2    = (const float*)d_in[6];
    const float* w3    = (const float*)d_in[7];
    const float* b3    = (const float*)d_in[8];
    float* out = (float*)d_out;

    char* ws = (char*)d_ws;
    // workspace layout (16B-aligned offsets)
    short* w3cT  = (short*)(ws);                       // 272*576*2      = 313,344
    short* w2bT  = (short*)(ws + 313344);              // 256*256*2      = 131,072
    short* featT = (short*)(ws + 444416);              // 16*66*66*64*2  = 8,921,088
    short* F     = (short*)(ws + 9365504);             // 16*4096*264*2  = 34,603,008
    (void)ws_size; (void)in_sizes; (void)n_in; (void)out_size;

    prep_transpose_k<<<BB * HT, 256, 0, stream>>>(feat, w2, w3, b3, featT, w3cT, w2bT);
    conv_k<<<BB * HH, 256, 0, stream>>>(featT, w3cT, F);
    mlp_k<<<(BB * QQ) / 64, 256, 0, stream>>>(coord, cell, w1, b1, b2, w2bT, F, out);
}